// Round 11
// baseline (472.350 us; speedup 1.0000x reference)
//
#include <hip/hip_runtime.h>
#include <hip/hip_bf16.h>

typedef float f32x4 __attribute__((ext_vector_type(4)));
typedef int   i32x4 __attribute__((ext_vector_type(4)));
typedef __bf16 bf16x8 __attribute__((ext_vector_type(8)));

#define BM 256
#define BN 128
// Slabs: A = 256 rows x 64 B = 16 KB; B = 128 rows x 64 B = 8 KB.
// Ring of 4: A [0,64K), B [64K,96K). 64 B/row = 32 bf16 (KS=32) or 64 i8 (KS=64).

__device__ __forceinline__ unsigned short f2bf(float f) {
    unsigned int u = __float_as_uint(f);
    u += 0x7fffu + ((u >> 16) & 1u);
    return (unsigned short)(u >> 16);
}

__device__ __forceinline__ void load_lds16(const void* g, void* l) {
    __builtin_amdgcn_global_load_lds((const __attribute__((address_space(1))) void*)g,
                                     (__attribute__((address_space(3))) void*)l,
                                     16, 0, 0);
}

// ---------------- conversion kernels ----------------
__global__ void cvt_f32_to_i8_k(const float* __restrict__ in,
                                signed char* __restrict__ out, int n) {
    int stride = gridDim.x * blockDim.x;
    for (int i = blockIdx.x * blockDim.x + threadIdx.x; i * 8 < n; i += stride) {
        float4 v0 = *reinterpret_cast<const float4*>(in + (size_t)i * 8);
        float4 v1 = *reinterpret_cast<const float4*>(in + (size_t)i * 8 + 4);
        union { signed char c[8]; int2 w; } u;
        float s = 127.0f / 6.0f;
        float f[8] = {v0.x, v0.y, v0.z, v0.w, v1.x, v1.y, v1.z, v1.w};
#pragma unroll
        for (int j = 0; j < 8; ++j) {
            int q = __float2int_rn(f[j] * s);
            q = q > 127 ? 127 : (q < -127 ? -127 : q);
            u.c[j] = (signed char)q;
        }
        *reinterpret_cast<int2*>(out + (size_t)i * 8) = u.w;
    }
}

__global__ void cvt_i32_to_i8_k(const int* __restrict__ in,
                                signed char* __restrict__ out, int n,
                                const int* __restrict__ zp) {
    int z = zp[0];
    int stride = gridDim.x * blockDim.x;
    for (int i = blockIdx.x * blockDim.x + threadIdx.x; i * 8 < n; i += stride) {
        int4 v0 = *reinterpret_cast<const int4*>(in + (size_t)i * 8);
        int4 v1 = *reinterpret_cast<const int4*>(in + (size_t)i * 8 + 4);
        union { signed char c[8]; int2 w; } u;
        int f[8] = {v0.x, v0.y, v0.z, v0.w, v1.x, v1.y, v1.z, v1.w};
#pragma unroll
        for (int j = 0; j < 8; ++j) {
            int q = f[j] - z;
            q = q > 127 ? 127 : (q < -128 ? -128 : q);
            u.c[j] = (signed char)q;
        }
        *reinterpret_cast<int2*>(out + (size_t)i * 8) = u.w;
    }
}

__global__ void cvt_i32_to_bf16_k(const int* __restrict__ in,
                                  unsigned short* __restrict__ out, int n,
                                  const int* __restrict__ zp) {
    int z = zp[0];
    int stride = gridDim.x * blockDim.x;
    for (int i = blockIdx.x * blockDim.x + threadIdx.x; i * 4 < n; i += stride) {
        int4 v = *reinterpret_cast<const int4*>(in + (size_t)i * 4);
        ushort4 o = make_ushort4(f2bf((float)(v.x - z)), f2bf((float)(v.y - z)),
                                 f2bf((float)(v.z - z)), f2bf((float)(v.w - z)));
        *reinterpret_cast<ushort4*>(out + (size_t)i * 4) = o;
    }
}

// ---------------- GEMM skeleton: 256x128 tile, frag double-buffer -----------
// 8 waves as 4(row)x2(col), 64x64 per wave: acc 64 f32/wave. Ring-4 slabs,
// 3 prefetched ahead, 3 loads/slab/thread (2 A + 1 B). Per kstep s:
//   vmcnt(3)  -> own slab-(s+1) loads done; barrier -> published for all
//   ds_read frags(s+1) into the OTHER register buffer (8 x ds_read_b128)
//   stage slab s+3 (3 x global_load_lds)
//   MFMA slab s from CURRENT buffer (read last kstep; no lgkm dependency on
//   this kstep's reads) -> LDS pipe overlaps MFMA pipe instead of serializing.
// Tail: vmcnt(0) at NSLAB-2, bare MFMA at NSLAB-1. Hazard audit: stage(s+3)
// writes slot (s-1)&3 whose frag-reads retired before any wave's barrier-s.

#define GEMM_PRE()                                                             \
    const int kb  = (lane >> 4) * 16;                                          \
    const int l15 = lane & 15;                                                 \
    int offA[4], offB[4];                                                      \
    _Pragma("unroll") for (int m = 0; m < 4; ++m) {                            \
        int g = wr * 64 + m * 16 + l15;                                        \
        int rp = g >> 1;                                                       \
        int inner = ((g & 1) << 6) | kb;                                       \
        offA[m] = rp * 128 + ((((inner >> 4) ^ rp) & 7) << 4);                 \
    }                                                                          \
    _Pragma("unroll") for (int n = 0; n < 4; ++n) {                            \
        int g = wc * 64 + n * 16 + l15;                                        \
        int rp = g >> 1;                                                       \
        int inner = ((g & 1) << 6) | kb;                                       \
        offB[n] = rp * 128 + ((((inner >> 4) ^ rp) & 7) << 4);                 \
    }                                                                          \
    const int dA0 = wave * 1024, dA1 = 8192 + wave * 1024, dB0 = wave * 1024;  \
    const char *pA0, *pA1, *pB0;                                               \
    {                                                                          \
        int p0 = tid, p1 = 512 + tid;                                          \
        int rpa0 = p0 >> 3, ja0 = (p0 & 7) ^ (rpa0 & 7);                       \
        int rpa1 = p1 >> 3, ja1 = (p1 & 7) ^ (rpa1 & 7);                       \
        int rpb  = p0 >> 3, jb  = (p0 & 7) ^ (rpb & 7);                        \
        pA0 = (const char*)A + (size_t)(brow + 2 * rpa0 + (ja0 >> 2)) * rowbA  \
              + (ja0 & 3) * 16 + 192;                                          \
        pA1 = (const char*)A + (size_t)(brow + 2 * rpa1 + (ja1 >> 2)) * rowbA  \
              + (ja1 & 3) * 16 + 192;                                          \
        pB0 = (const char*)Bt + (size_t)(bcol + 2 * rpb + (jb >> 2)) * rowbB   \
              + (jb & 3) * 16 + 192;                                           \
    }                                                                          \
    _Pragma("unroll") for (int s = 0; s < 3; ++s) {                            \
        char* da = smem + s * 16384;                                           \
        char* db = smem + 65536 + s * 8192;                                    \
        load_lds16(pA0 + s * 64 - 192, da + dA0);                              \
        load_lds16(pA1 + s * 64 - 192, da + dA1);                              \
        load_lds16(pB0 + s * 64 - 192, db + dB0);                              \
    }

#define KREAD0(RA, RB, FRAGT)                                                  \
    { const char* As_ = smem;                                                  \
      const char* Bs_ = smem + 65536;                                          \
      _Pragma("unroll") for (int m = 0; m < 4; ++m)                            \
          RA[m] = *reinterpret_cast<const FRAGT*>(As_ + offA[m]);              \
      _Pragma("unroll") for (int n = 0; n < 4; ++n)                            \
          RB[n] = *reinterpret_cast<const FRAGT*>(Bs_ + offB[n]);              \
    }

#define KSTEP_D(SS, VMSTR, DO_STAGE, RA, RB, CA, CB, FRAGT, MFMA)              \
  { asm volatile("s_waitcnt " VMSTR ::: "memory");                             \
    __builtin_amdgcn_s_barrier();                                              \
    const char* As_ = smem + ((((SS) + 1) & 3) << 14);                         \
    const char* Bs_ = smem + 65536 + ((((SS) + 1) & 3) << 13);                 \
    _Pragma("unroll") for (int m = 0; m < 4; ++m)                              \
        RA[m] = *reinterpret_cast<const FRAGT*>(As_ + offA[m]);                \
    _Pragma("unroll") for (int n = 0; n < 4; ++n)                              \
        RB[n] = *reinterpret_cast<const FRAGT*>(Bs_ + offB[n]);                \
    if (DO_STAGE) {                                                            \
        const int db_ = (((SS) + 3) & 3);                                      \
        load_lds16(pA0, smem + (db_ << 14) + dA0);                             \
        load_lds16(pA1, smem + (db_ << 14) + dA1);                             \
        load_lds16(pB0, smem + 65536 + (db_ << 13) + dB0);                     \
        pA0 += 64; pA1 += 64; pB0 += 64;                                       \
    }                                                                          \
    __builtin_amdgcn_s_setprio(1);                                             \
    _Pragma("unroll") for (int m = 0; m < 4; ++m)                              \
      _Pragma("unroll") for (int n = 0; n < 4; ++n)                            \
        acc[m][n] = MFMA(CA[m], CB[n], acc[m][n]);                             \
    __builtin_amdgcn_s_setprio(0);                                             \
  }

#define KFIN(CA, CB, MFMA)                                                     \
  { __builtin_amdgcn_s_setprio(1);                                             \
    _Pragma("unroll") for (int m = 0; m < 4; ++m)                              \
      _Pragma("unroll") for (int n = 0; n < 4; ++n)                            \
        acc[m][n] = MFMA(CA[m], CB[n], acc[m][n]);                             \
    __builtin_amdgcn_s_setprio(0);                                             \
  }

#define MFMA_BF16(aa, bb, cc) __builtin_amdgcn_mfma_f32_16x16x32_bf16(aa, bb, cc, 0, 0, 0)
#define MFMA_I8(aa, bb, cc)   __builtin_amdgcn_mfma_i32_16x16x64_i8(aa, bb, cc, 0, 0, 0)

#define GEMM_LOOP(FRAGT, MFMA)                                                 \
    KREAD0(a0, b0, FRAGT)                                                      \
    for (int s = 0; s < NSLAB - 3; s += 2) {                                   \
        KSTEP_D(s,     "vmcnt(3)", true,              a1, b1, a0, b0, FRAGT, MFMA); \
        KSTEP_D(s + 1, "vmcnt(3)", (s + 4 < NSLAB),   a0, b0, a1, b1, FRAGT, MFMA); \
    }                                                                          \
    KSTEP_D(NSLAB - 2, "vmcnt(0)", false, a1, b1, a0, b0, FRAGT, MFMA);        \
    KFIN(a1, b1, MFMA);

// ---------------- GEMM1: h = gelu(dequant(xq * wfcq^T)+b) -------------------
__global__ __launch_bounds__(512, 2) void gemm_fc_i8(
    const signed char* __restrict__ A,   // xq [M,K] i8
    const signed char* __restrict__ Bt,  // wfcq [N,K] i8
    unsigned short* __restrict__ Cout,   // h bf16
    const int* __restrict__ bias_q,
    const float* __restrict__ s_w_p,
    const float* __restrict__ s_b_p,
    const int* __restrict__ z_b_p,
    int M, int N, int K)
{
    extern __shared__ char smem[];

    const int tid  = threadIdx.x;
    const int wave = tid >> 6;
    const int lane = tid & 63;
    const int wr = wave >> 1;        // 0..3 : row quarter (64 rows)
    const int wc = wave & 1;         // 0..1 : col half (64 cols)

    const int bid  = blockIdx.x;
    const int x8   = bid & 7;
    const int j32  = (bid >> 3) & 31;
    const int rnd  = bid >> 8;
    const int brow = (4 * x8 + (j32 >> 3)) * BM;
    const int bcol = (rnd * 8 + (j32 & 7)) * BN;

    const int NSLAB = K / 64;            // 64 i8 per slab-row
    const size_t rowbA = (size_t)K;
    const size_t rowbB = (size_t)K;

    i32x4 acc[4][4] = {};
    i32x4 a0[4], b0[4], a1[4], b1[4];

    GEMM_PRE()
    asm volatile("s_waitcnt vmcnt(6)" ::: "memory");
    __builtin_amdgcn_s_barrier();
    GEMM_LOOP(i32x4, MFMA_I8)

    // epilogue: dequant + bias + tanh-GELU -> bf16 via LDS, coalesced dwordx4
    const float s_w = s_w_p[0] * (6.0f / 127.0f);
    const float s_b = s_b_p[0];
    const int   z_b = z_b_p[0];

    __syncthreads();
    unsigned short* hl = (unsigned short*)smem;     // 256x128 bf16 = 64 KB
#pragma unroll
    for (int n = 0; n < 4; ++n) {
        int col_local = wc * 64 + n * 16 + l15;     // 0..127
        float bias = s_b * (float)(bias_q[bcol + col_local] - z_b);
        int c16 = col_local >> 3;                   // 0..15
        int cb  = col_local & 7;
#pragma unroll
        for (int m = 0; m < 4; ++m) {
#pragma unroll
            for (int r = 0; r < 4; ++r) {
                int row_local = wr * 64 + m * 16 + (lane >> 4) * 4 + r;  // 0..255
                float v = (float)acc[m][n][r] * s_w + bias;
                float t2 = v * (1.5957691f + 0.0713548162f * v * v);
                float g  = v / (1.0f + __expf(-t2));
                int sw = c16 ^ (row_local & 15);
                hl[row_local * 128 + sw * 8 + cb] = f2bf(g);
            }
        }
    }
    __syncthreads();
#pragma unroll
    for (int it = 0; it < 8; ++it) {
        int lin = it * 512 + tid;      // 16B-chunk index, 0..4095
        int rl  = lin >> 4;            // 16 chunks per row
        int c16 = lin & 15;
        int sw  = c16 ^ (rl & 15);
        uint4 d = *reinterpret_cast<const uint4*>(hl + rl * 128 + sw * 8);
        *reinterpret_cast<uint4*>(Cout + (size_t)(brow + rl) * N + bcol + c16 * 8) = d;
    }
}

// ---------------- GEMM2: out = dequant(h * wproj^T)+b -----------------------
__global__ __launch_bounds__(512, 2) void gemm_proj(
    const unsigned short* __restrict__ A,
    const unsigned short* __restrict__ Bt,
    float* __restrict__ Cout,
    const int* __restrict__ bias_q,
    const float* __restrict__ s_w_p,
    const float* __restrict__ s_b_p,
    const int* __restrict__ z_b_p,
    int M, int N, int K)
{
    extern __shared__ char smem[];

    const int tid  = threadIdx.x;
    const int wave = tid >> 6;
    const int lane = tid & 63;
    const int wr = wave >> 1;
    const int wc = wave & 1;

    const int bid  = blockIdx.x;
    const int x8   = bid & 7;
    const int j32  = (bid >> 3) & 31;
    const int rnd  = bid >> 8;
    const int brow = (4 * x8 + (j32 >> 3)) * BM;
    const int bcol = (rnd * 8 + (j32 & 7)) * BN;

    const int NSLAB = K / 32;            // 32 bf16 per slab-row
    const size_t rowbA = (size_t)K * 2;
    const size_t rowbB = (size_t)K * 2;

    f32x4 acc[4][4] = {};
    bf16x8 a0[4], b0[4], a1[4], b1[4];

    GEMM_PRE()
    asm volatile("s_waitcnt vmcnt(6)" ::: "memory");
    __builtin_amdgcn_s_barrier();
    GEMM_LOOP(bf16x8, MFMA_BF16)

    const float s_w = s_w_p[0];
    const float s_b = s_b_p[0];
    const int   z_b = z_b_p[0];
    const int row0 = brow + wr * 64;
    const int col0 = bcol + wc * 64;
#pragma unroll
    for (int n = 0; n < 4; ++n) {
        int col = col0 + n * 16 + l15;
        float bias = s_b * (float)(bias_q[col] - z_b);
#pragma unroll
        for (int m = 0; m < 4; ++m) {
#pragma unroll
            for (int r = 0; r < 4; ++r) {
                int row = row0 + m * 16 + (lane >> 4) * 4 + r;
                Cout[(size_t)row * N + col] = acc[m][n][r] * s_w + bias;
            }
        }
    }
}

extern "C" void kernel_launch(void* const* d_in, const int* in_sizes, int n_in,
                              void* d_out, int out_size, void* d_ws, size_t ws_size,
                              hipStream_t stream) {
    const float* x        = (const float*)d_in[0];
    const int*   w_fc_q   = (const int*)d_in[1];
    const int*   b_fc_q   = (const int*)d_in[2];
    const int*   w_proj_q = (const int*)d_in[3];
    const int*   b_proj_q = (const int*)d_in[4];
    const float* s_fc_w   = (const float*)d_in[5];
    const float* s_fc_b   = (const float*)d_in[6];
    const float* s_proj_w = (const float*)d_in[7];
    const float* s_proj_b = (const float*)d_in[8];
    const int*   z_fc_w   = (const int*)d_in[9];
    const int*   z_fc_b   = (const int*)d_in[10];
    const int*   z_proj_w = (const int*)d_in[11];
    const int*   z_proj_b = (const int*)d_in[12];

    const int M = 4 * 2048;
    const int E = 2048;
    const int H = 4 * 2048;

    // ws: xq i8 [M*E] | wfcq i8 [H*E] | wproj bf16 [E*H] | hb bf16 [M*H]
    size_t need = (size_t)M * E + (size_t)H * E
                + ((size_t)E * H + (size_t)M * H) * 2;
    if (ws_size < need) return;

    signed char*    xq    = (signed char*)d_ws;
    signed char*    wfcq  = xq + (size_t)M * E;
    unsigned short* wproj = (unsigned short*)(wfcq + (size_t)H * E);
    unsigned short* hb    = wproj + (size_t)E * H;

    hipFuncSetAttribute(reinterpret_cast<const void*>(gemm_fc_i8),
                        hipFuncAttributeMaxDynamicSharedMemorySize, 98304);
    hipFuncSetAttribute(reinterpret_cast<const void*>(gemm_proj),
                        hipFuncAttributeMaxDynamicSharedMemorySize, 98304);

    cvt_f32_to_i8_k<<<2048, 256, 0, stream>>>(x, xq, M * E);
    cvt_i32_to_i8_k<<<2048, 256, 0, stream>>>(w_fc_q, wfcq, H * E, z_fc_w);
    cvt_i32_to_bf16_k<<<2048, 256, 0, stream>>>(w_proj_q, wproj, E * H, z_proj_w);

    // GEMM1: i8 MFMA (exact int32 accum), fused dequant+bias+GELU -> bf16 h
    gemm_fc_i8<<<dim3((M / BM) * (H / BN)), 512, 98304, stream>>>(
        xq, wfcq, hb, b_fc_q, s_fc_w, s_fc_b, z_fc_b, M, H, E);

    // GEMM2: bf16 MFMA ; scale+bias -> f32 out
    gemm_proj<<<dim3((M / BM) * (E / BN)), 512, 98304, stream>>>(
        hb, wproj, (float*)d_out, b_proj_q, s_proj_w, s_proj_b, z_proj_b, M, E, H);
}

// Round 12
// 452.744 us; speedup vs baseline: 1.0433x; 1.0433x over previous
//
#include <hip/hip_runtime.h>
#include <hip/hip_bf16.h>

typedef float f32x4 __attribute__((ext_vector_type(4)));
typedef int   i32x4 __attribute__((ext_vector_type(4)));
typedef __bf16 bf16x8 __attribute__((ext_vector_type(8)));

#define BM 256
#define BN 128
// Slabs: A = 256 rows x 64 B = 16 KB; B = 128 rows x 64 B = 8 KB.
// Ring-2: A [0,32K), B [32K,48K). 64 B/row = 32 bf16 (KS=32) or 64 i8 (KS=64).
// 64 KB dynamic LDS (fc epilogue tile needs 64 KB) -> 2 blocks/CU: the
// co-resident block's MFMAs cover this block's vmcnt(0) drain (m97-style TLP,
// impossible at rounds 3-11's 128 KB / 1 block/CU).

__device__ __forceinline__ unsigned short f2bf(float f) {
    unsigned int u = __float_as_uint(f);
    u += 0x7fffu + ((u >> 16) & 1u);
    return (unsigned short)(u >> 16);
}

__device__ __forceinline__ void load_lds16(const void* g, void* l) {
    __builtin_amdgcn_global_load_lds((const __attribute__((address_space(1))) void*)g,
                                     (__attribute__((address_space(3))) void*)l,
                                     16, 0, 0);
}

// ---------------- conversion kernels ----------------
__global__ void cvt_f32_to_i8_k(const float* __restrict__ in,
                                signed char* __restrict__ out, int n) {
    int stride = gridDim.x * blockDim.x;
    for (int i = blockIdx.x * blockDim.x + threadIdx.x; i * 8 < n; i += stride) {
        float4 v0 = *reinterpret_cast<const float4*>(in + (size_t)i * 8);
        float4 v1 = *reinterpret_cast<const float4*>(in + (size_t)i * 8 + 4);
        union { signed char c[8]; int2 w; } u;
        float s = 127.0f / 6.0f;
        float f[8] = {v0.x, v0.y, v0.z, v0.w, v1.x, v1.y, v1.z, v1.w};
#pragma unroll
        for (int j = 0; j < 8; ++j) {
            int q = __float2int_rn(f[j] * s);
            q = q > 127 ? 127 : (q < -127 ? -127 : q);
            u.c[j] = (signed char)q;
        }
        *reinterpret_cast<int2*>(out + (size_t)i * 8) = u.w;
    }
}

__global__ void cvt_i32_to_i8_k(const int* __restrict__ in,
                                signed char* __restrict__ out, int n,
                                const int* __restrict__ zp) {
    int z = zp[0];
    int stride = gridDim.x * blockDim.x;
    for (int i = blockIdx.x * blockDim.x + threadIdx.x; i * 8 < n; i += stride) {
        int4 v0 = *reinterpret_cast<const int4*>(in + (size_t)i * 8);
        int4 v1 = *reinterpret_cast<const int4*>(in + (size_t)i * 8 + 4);
        union { signed char c[8]; int2 w; } u;
        int f[8] = {v0.x, v0.y, v0.z, v0.w, v1.x, v1.y, v1.z, v1.w};
#pragma unroll
        for (int j = 0; j < 8; ++j) {
            int q = f[j] - z;
            q = q > 127 ? 127 : (q < -128 ? -128 : q);
            u.c[j] = (signed char)q;
        }
        *reinterpret_cast<int2*>(out + (size_t)i * 8) = u.w;
    }
}

__global__ void cvt_i32_to_bf16_k(const int* __restrict__ in,
                                  unsigned short* __restrict__ out, int n,
                                  const int* __restrict__ zp) {
    int z = zp[0];
    int stride = gridDim.x * blockDim.x;
    for (int i = blockIdx.x * blockDim.x + threadIdx.x; i * 4 < n; i += stride) {
        int4 v = *reinterpret_cast<const int4*>(in + (size_t)i * 4);
        ushort4 o = make_ushort4(f2bf((float)(v.x - z)), f2bf((float)(v.y - z)),
                                 f2bf((float)(v.z - z)), f2bf((float)(v.w - z)));
        *reinterpret_cast<ushort4*>(out + (size_t)i * 4) = o;
    }
}

// ---------------- GEMM skeleton: 256x128 tile, ring-2, 2 blocks/CU ----------
// 8 waves as 4(row)x2(col), 64x64 per wave. Per kstep s:
//   vmcnt(0) -> slab s's 3 loads (issued last kstep) landed; barrier publishes
//   stage slab s+1 into the other slot (3 x global_load_lds)
//   ds_read frags of slab s (8 x ds_read_b128); setprio; 16 MFMA; setprio.
// Hazard: slot (s+1)&1's reads (kstep s-1) are lgkm-retired before each
// wave's MFMA(s-1), hence before barrier-s -> overwrite safe.

#define GEMM_PRE()                                                             \
    const int kb  = (lane >> 4) * 16;                                          \
    const int l15 = lane & 15;                                                 \
    int offA[4], offB[4];                                                      \
    _Pragma("unroll") for (int m = 0; m < 4; ++m) {                            \
        int g = wr * 64 + m * 16 + l15;                                        \
        int rp = g >> 1;                                                       \
        int inner = ((g & 1) << 6) | kb;                                       \
        offA[m] = rp * 128 + ((((inner >> 4) ^ rp) & 7) << 4);                 \
    }                                                                          \
    _Pragma("unroll") for (int n = 0; n < 4; ++n) {                            \
        int g = wc * 64 + n * 16 + l15;                                        \
        int rp = g >> 1;                                                       \
        int inner = ((g & 1) << 6) | kb;                                       \
        offB[n] = rp * 128 + ((((inner >> 4) ^ rp) & 7) << 4);                 \
    }                                                                          \
    const int dA0 = wave * 1024, dA1 = 8192 + wave * 1024, dB0 = wave * 1024;  \
    const char *pA0, *pA1, *pB0;                                               \
    {                                                                          \
        int p0 = tid, p1 = 512 + tid;                                          \
        int rpa0 = p0 >> 3, ja0 = (p0 & 7) ^ (rpa0 & 7);                       \
        int rpa1 = p1 >> 3, ja1 = (p1 & 7) ^ (rpa1 & 7);                       \
        int rpb  = p0 >> 3, jb  = (p0 & 7) ^ (rpb & 7);                        \
        pA0 = (const char*)A + (size_t)(brow + 2 * rpa0 + (ja0 >> 2)) * rowbA  \
              + (ja0 & 3) * 16;                                                \
        pA1 = (const char*)A + (size_t)(brow + 2 * rpa1 + (ja1 >> 2)) * rowbA  \
              + (ja1 & 3) * 16;                                                \
        pB0 = (const char*)Bt + (size_t)(bcol + 2 * rpb + (jb >> 2)) * rowbB   \
              + (jb & 3) * 16;                                                 \
    }                                                                          \
    /* prologue: stage slab 0 into slot 0 */                                   \
    load_lds16(pA0, smem + dA0);                                               \
    load_lds16(pA1, smem + dA1);                                               \
    load_lds16(pB0, smem + 32768 + dB0);                                       \
    pA0 += 64; pA1 += 64; pB0 += 64;

#define KSTEP2(SS, DO_STAGE, FRAGT, MFMA)                                      \
  { asm volatile("s_waitcnt vmcnt(0)" ::: "memory");                           \
    __builtin_amdgcn_s_barrier();                                              \
    if (DO_STAGE) {                                                            \
        const int db_ = (((SS) + 1) & 1);                                      \
        load_lds16(pA0, smem + db_ * 16384 + dA0);                             \
        load_lds16(pA1, smem + db_ * 16384 + dA1);                             \
        load_lds16(pB0, smem + 32768 + db_ * 8192 + dB0);                      \
        pA0 += 64; pA1 += 64; pB0 += 64;                                       \
    }                                                                          \
    const char* As_ = smem + ((SS) & 1) * 16384;                               \
    const char* Bs_ = smem + 32768 + ((SS) & 1) * 8192;                        \
    FRAGT a[4], b[4];                                                          \
    _Pragma("unroll") for (int m = 0; m < 4; ++m)                              \
        a[m] = *reinterpret_cast<const FRAGT*>(As_ + offA[m]);                 \
    _Pragma("unroll") for (int n = 0; n < 4; ++n)                              \
        b[n] = *reinterpret_cast<const FRAGT*>(Bs_ + offB[n]);                 \
    __builtin_amdgcn_s_setprio(1);                                             \
    _Pragma("unroll") for (int m = 0; m < 4; ++m)                              \
      _Pragma("unroll") for (int n = 0; n < 4; ++n)                            \
        acc[m][n] = MFMA(a[m], b[n], acc[m][n]);                               \
    __builtin_amdgcn_s_setprio(0);                                             \
  }

#define MFMA_BF16(aa, bb, cc) __builtin_amdgcn_mfma_f32_16x16x32_bf16(aa, bb, cc, 0, 0, 0)
#define MFMA_I8(aa, bb, cc)   __builtin_amdgcn_mfma_i32_16x16x64_i8(aa, bb, cc, 0, 0, 0)

// ---------------- GEMM1: h = gelu(dequant(xq * wfcq^T)+b) -------------------
__global__ __launch_bounds__(512, 2) void gemm_fc_i8(
    const signed char* __restrict__ A,   // xq [M,K] i8
    const signed char* __restrict__ Bt,  // wfcq [N,K] i8
    unsigned short* __restrict__ Cout,   // h bf16
    const int* __restrict__ bias_q,
    const float* __restrict__ s_w_p,
    const float* __restrict__ s_b_p,
    const int* __restrict__ z_b_p,
    int M, int N, int K)
{
    extern __shared__ char smem[];

    const int tid  = threadIdx.x;
    const int wave = tid >> 6;
    const int lane = tid & 63;
    const int wr = wave >> 1;        // 0..3 : 64-row band
    const int wc = wave & 1;         // 0..1 : 64-col half

    const int bid  = blockIdx.x;
    const int x8   = bid & 7;
    const int j32  = (bid >> 3) & 31;
    const int rnd  = bid >> 8;
    const int brow = (4 * x8 + (j32 >> 3)) * BM;
    const int bcol = (rnd * 8 + (j32 & 7)) * BN;

    const int NSLAB = K / 64;            // 64 i8 per slab-row
    const size_t rowbA = (size_t)K;
    const size_t rowbB = (size_t)K;

    i32x4 acc[4][4] = {};

    GEMM_PRE()

    for (int s = 0; s < NSLAB; ++s) {
        KSTEP2(s, (s + 1 < NSLAB), i32x4, MFMA_I8);
    }

    // epilogue: dequant + bias + tanh-GELU -> bf16 via LDS, coalesced dwordx4
    const float s_w = s_w_p[0] * (6.0f / 127.0f);
    const float s_b = s_b_p[0];
    const int   z_b = z_b_p[0];

    __syncthreads();
    unsigned short* hl = (unsigned short*)smem;     // 256x128 bf16 = 64 KB
#pragma unroll
    for (int n = 0; n < 4; ++n) {
        int col_local = wc * 64 + n * 16 + l15;     // 0..127
        float bias = s_b * (float)(bias_q[bcol + col_local] - z_b);
        int c16 = col_local >> 3;                   // 0..15
        int cb  = col_local & 7;
#pragma unroll
        for (int m = 0; m < 4; ++m) {
#pragma unroll
            for (int r = 0; r < 4; ++r) {
                int row_local = wr * 64 + m * 16 + (lane >> 4) * 4 + r;  // 0..255
                float v = (float)acc[m][n][r] * s_w + bias;
                float t2 = v * (1.5957691f + 0.0713548162f * v * v);
                float g  = v / (1.0f + __expf(-t2));
                int sw = c16 ^ (row_local & 15);
                hl[row_local * 128 + sw * 8 + cb] = f2bf(g);
            }
        }
    }
    __syncthreads();
#pragma unroll
    for (int it = 0; it < 8; ++it) {
        int lin = it * 512 + tid;      // 16B-chunk index, 0..4095
        int rl  = lin >> 4;            // 16 chunks per row
        int c16 = lin & 15;
        int sw  = c16 ^ (rl & 15);
        uint4 d = *reinterpret_cast<const uint4*>(hl + rl * 128 + sw * 8);
        *reinterpret_cast<uint4*>(Cout + (size_t)(brow + rl) * N + bcol + c16 * 8) = d;
    }
}

// ---------------- GEMM2: out = dequant(h * wproj^T)+b -----------------------
__global__ __launch_bounds__(512, 2) void gemm_proj(
    const unsigned short* __restrict__ A,
    const unsigned short* __restrict__ Bt,
    float* __restrict__ Cout,
    const int* __restrict__ bias_q,
    const float* __restrict__ s_w_p,
    const float* __restrict__ s_b_p,
    const int* __restrict__ z_b_p,
    int M, int N, int K)
{
    extern __shared__ char smem[];

    const int tid  = threadIdx.x;
    const int wave = tid >> 6;
    const int lane = tid & 63;
    const int wr = wave >> 1;
    const int wc = wave & 1;

    const int bid  = blockIdx.x;
    const int x8   = bid & 7;
    const int j32  = (bid >> 3) & 31;
    const int rnd  = bid >> 8;
    const int brow = (4 * x8 + (j32 >> 3)) * BM;
    const int bcol = (rnd * 8 + (j32 & 7)) * BN;

    const int NSLAB = K / 32;            // 32 bf16 per slab-row
    const size_t rowbA = (size_t)K * 2;
    const size_t rowbB = (size_t)K * 2;

    f32x4 acc[4][4] = {};

    GEMM_PRE()

    for (int s = 0; s < NSLAB; ++s) {
        KSTEP2(s, (s + 1 < NSLAB), bf16x8, MFMA_BF16);
    }

    const float s_w = s_w_p[0];
    const float s_b = s_b_p[0];
    const int   z_b = z_b_p[0];
    const int row0 = brow + wr * 64;
    const int col0 = bcol + wc * 64;
#pragma unroll
    for (int n = 0; n < 4; ++n) {
        int col = col0 + n * 16 + l15;
        float bias = s_b * (float)(bias_q[col] - z_b);
#pragma unroll
        for (int m = 0; m < 4; ++m) {
#pragma unroll
            for (int r = 0; r < 4; ++r) {
                int row = row0 + m * 16 + (lane >> 4) * 4 + r;
                Cout[(size_t)row * N + col] = acc[m][n][r] * s_w + bias;
            }
        }
    }
}

extern "C" void kernel_launch(void* const* d_in, const int* in_sizes, int n_in,
                              void* d_out, int out_size, void* d_ws, size_t ws_size,
                              hipStream_t stream) {
    const float* x        = (const float*)d_in[0];
    const int*   w_fc_q   = (const int*)d_in[1];
    const int*   b_fc_q   = (const int*)d_in[2];
    const int*   w_proj_q = (const int*)d_in[3];
    const int*   b_proj_q = (const int*)d_in[4];
    const float* s_fc_w   = (const float*)d_in[5];
    const float* s_fc_b   = (const float*)d_in[6];
    const float* s_proj_w = (const float*)d_in[7];
    const float* s_proj_b = (const float*)d_in[8];
    const int*   z_fc_w   = (const int*)d_in[9];
    const int*   z_fc_b   = (const int*)d_in[10];
    const int*   z_proj_w = (const int*)d_in[11];
    const int*   z_proj_b = (const int*)d_in[12];

    const int M = 4 * 2048;
    const int E = 2048;
    const int H = 4 * 2048;

    // ws: xq i8 [M*E] | wfcq i8 [H*E] | wproj bf16 [E*H] | hb bf16 [M*H]
    size_t need = (size_t)M * E + (size_t)H * E
                + ((size_t)E * H + (size_t)M * H) * 2;
    if (ws_size < need) return;

    signed char*    xq    = (signed char*)d_ws;
    signed char*    wfcq  = xq + (size_t)M * E;
    unsigned short* wproj = (unsigned short*)(wfcq + (size_t)H * E);
    unsigned short* hb    = wproj + (size_t)E * H;

    hipFuncSetAttribute(reinterpret_cast<const void*>(gemm_fc_i8),
                        hipFuncAttributeMaxDynamicSharedMemorySize, 65536);
    hipFuncSetAttribute(reinterpret_cast<const void*>(gemm_proj),
                        hipFuncAttributeMaxDynamicSharedMemorySize, 65536);

    cvt_f32_to_i8_k<<<2048, 256, 0, stream>>>(x, xq, M * E);
    cvt_i32_to_i8_k<<<2048, 256, 0, stream>>>(w_fc_q, wfcq, H * E, z_fc_w);
    cvt_i32_to_bf16_k<<<2048, 256, 0, stream>>>(w_proj_q, wproj, E * H, z_proj_w);

    // GEMM1: i8 MFMA (exact int32 accum), fused dequant+bias+GELU -> bf16 h
    gemm_fc_i8<<<dim3((M / BM) * (H / BN)), 512, 65536, stream>>>(
        xq, wfcq, hb, b_fc_q, s_fc_w, s_fc_b, z_fc_b, M, H, E);

    // GEMM2: bf16 MFMA ; scale+bias -> f32 out
    gemm_proj<<<dim3((M / BM) * (E / BN)), 512, 65536, stream>>>(
        hb, wproj, (float*)d_out, b_proj_q, s_proj_w, s_proj_b, z_proj_b, M, E, H);
}